// Round 17
// baseline (284.023 us; speedup 1.0000x reference)
//
#include <hip/hip_runtime.h>
#include <math.h>

#define N_GT 256
#define M_PR 1024
#define LG   91
#define TPB  256
#define CPT  4    // cols per thread (256 threads * 4 = 1024)

// f64 DPP min-reduce stage (validated CTRL/mask sequence from r8; masked
// lanes keep old -> fmin(mine,mine) identity). Value-only; wave-scoped.
#define DPPMIN(red, CTRL, RM, BM) do { \
    int _rh = __double2hiint(red), _rl = __double2loint(red); \
    int _oh = __builtin_amdgcn_update_dpp(_rh, _rh, CTRL, RM, BM, false); \
    int _ol = __builtin_amdgcn_update_dpp(_rl, _rl, CTRL, RM, BM, false); \
    (red) = fmin((red), __hiloint2double(_oh, _ol)); \
} while (0)

// ---------------------------------------------------------------------------
// Kernel 1: cost[i][j] = sqrt(|cgt_i - cpred_j|^2) + sum_l |lgt_i - lpred_j|
// F64=1 stores the f32 value widened to double (bit-identical semantics).
// Fused rowmin/rowarg (first-occurrence argmin) for the greedy init.
// ---------------------------------------------------------------------------
template<int F64>
__global__ __launch_bounds__(256) void cost_kernel(
    const float* __restrict__ cgt, const float* __restrict__ cpred,
    const float* __restrict__ lgt, const float* __restrict__ lpred,
    void* __restrict__ costout, float* __restrict__ rowmin, int* __restrict__ rowarg)
{
    __shared__ float sg[LG];
    __shared__ float gx, gy;
    __shared__ float wmin[4];
    __shared__ int   warg[4];
    const int i   = blockIdx.x;
    const int tid = threadIdx.x;
    if (tid < LG) sg[tid] = lgt[i * LG + tid];
    if (tid == 0) { gx = cgt[2 * i]; gy = cgt[2 * i + 1]; }
    __syncthreads();
    float bv = 1e30f; int bj = 0;
    for (int j = tid; j < M_PR; j += 256) {
        float dx = gx - cpred[2 * j];
        float dy = gy - cpred[2 * j + 1];
        float cd = sqrtf(dx * dx + dy * dy);
        const float* lp = lpred + j * LG;
        float s = 0.f;
        #pragma unroll 7
        for (int l = 0; l < LG; ++l) s += fabsf(sg[l] - lp[l]);
        float cv = cd + s;
        if (F64) ((double*)costout)[(size_t)i * M_PR + j] = (double)cv;
        else     ((float*) costout)[(size_t)i * M_PR + j] = cv;
        if (cv < bv) { bv = cv; bj = j; }
    }
    const int lane = tid & 63, wid = tid >> 6;
    #pragma unroll
    for (int off = 1; off < 64; off <<= 1) {
        float ov = __shfl_xor(bv, off, 64);
        int   oj = __shfl_xor(bj, off, 64);
        if (ov < bv || (ov == bv && oj < bj)) { bv = ov; bj = oj; }
    }
    if (lane == 0) { wmin[wid] = bv; warg[wid] = bj; }
    __syncthreads();
    if (tid == 0) {
        for (int w = 1; w < 4; ++w)
            if (wmin[w] < bv || (wmin[w] == bv && warg[w] < bj)) { bv = wmin[w]; bj = warg[w]; }
        rowmin[i] = bv; rowarg[i] = bj;
    }
}

// ---------------------------------------------------------------------------
// Kernel 2: JV LSA (r8..r16-validated trace: greedy claim u=rowmin, v=0,
// then exact Dijkstra per unmatched row in ascending row order).
// r17 = r14/r16 with an instruction diet (issue-bound kernel):
//  - COMBINED post-relax tournament (replaces r10's split old-A/cur
//    tournaments + merge, whose load-shadow rationale died with 4 waves):
//    relax updates A/bw, then ONE 4-entry strict-< scan (ascending k =>
//    smallest col on exact ties == reference first-occurrence argmin;
//    identical semantics to the r9-validated form).
//  - Cross-wave merge as a 3-compare tree with NO col compares: wave w owns
//    an ascending col range, so value-tie -> earlier wave IS smallest col.
//  - dead i0/cwbase bookkeeping dropped.
// Cross-wave reduce: per-wave DPP+ballot winner -> one double2 LDS record;
// ONE barrier/step, parity double-buffered wb[2][4].
// All f64 formulas identical to r13 (vb=v+base2, cur=cd-vb).
// Output (f32): [0..255]=row, [256..511]=col, [512]=cost.
// ---------------------------------------------------------------------------
template<int F64>
__global__ __launch_bounds__(256) void lsa_kernel(
    const void* __restrict__ costv,
    const float* __restrict__ rowmin, const int* __restrict__ rowarg,
    const float* __restrict__ cgt, const float* __restrict__ cpred,
    float* __restrict__ out)
{
    __shared__ double u[N_GT + 1];
    __shared__ double markD_lds[M_PR + 1];
    __shared__ double vsave_lds[M_PR + 1];
    __shared__ int    p[M_PR + 1];
    __shared__ int    pmin[M_PR + 1];
    __shared__ int    way[M_PR + 1];
    __shared__ int    pathbuf[N_GT + 8];
    __shared__ int    pathlen_s;
    __shared__ int    freeA[N_GT];
    __shared__ int    colarr[N_GT];
    __shared__ double2 wb[2][4];          // parity-double-buffered wave bests
    __shared__ int    wcnt[4];

    const int tid  = threadIdx.x;
    const int lane = tid & 63;
    const int wid  = tid >> 6;
    const double NEGINF = -__builtin_inf();
    const double INFD   =  __builtin_inf();

    double v[CPT], A[CPT];
    int    bw[CPT];

    const int colbase = tid * CPT;        // 0-based first owned col

    for (int j = tid; j <= M_PR; j += TPB) { p[j] = 0; pmin[j] = 0x7FFFFFFF; }
    colarr[tid] = 0;
    if (tid == 0) u[0] = 0.0;
    #pragma unroll
    for (int k = 0; k < CPT; ++k) { v[k] = 0.0; bw[k] = 0; }
    __syncthreads();

    // ---- greedy claim: row -> its argmin col, smallest row wins ----
    u[tid + 1] = (double)rowmin[tid];
    atomicMin(&pmin[rowarg[tid] + 1], tid + 1);
    __syncthreads();
    for (int j = tid + 1; j <= M_PR; j += TPB)
        p[j] = (pmin[j] == 0x7FFFFFFF) ? 0 : pmin[j];
    // free-row list (ascending row order), cross-wave ordered compaction
    {
        bool um = (pmin[rowarg[tid] + 1] != tid + 1);
        unsigned long long mask = __ballot(um);
        int local = __popcll(mask & ((1ull << lane) - 1ull));
        if (lane == 0) wcnt[wid] = __popcll(mask);
        __syncthreads();
        int base = 0;
        for (int w = 0; w < wid; ++w) base += wcnt[w];
        if (um) freeA[base + local] = tid + 1;       // 1-based row
        __syncthreads();
    }
    const int nfree = wcnt[0] + wcnt[1] + wcnt[2] + wcnt[3];

    // warm the first search's row
    if (nfree > 0) {
        int nr = freeA[0];
        if (F64) {
            const double* nrow = (const double*)costv + (size_t)(nr - 1) * M_PR + colbase;
            double t0 = nrow[0];
            asm volatile("" :: "v"(t0));
        } else {
            const float* nrow = (const float*)costv + (size_t)(nr - 1) * M_PR + colbase;
            float t0 = nrow[0];
            asm volatile("" :: "v"(t0));
        }
    }

    int par = 0;
    // ---- shortest augmenting path per free row ----
    for (int t = 0; t < nfree; ++t) {
        const int i = freeA[t];
        #pragma unroll
        for (int k = 0; k < CPT; ++k) A[k] = 1e18;
        unsigned usedmask = 0u;
        double D  = 0.0;
        int    j0 = 0;
        int    inext = i;                   // row to scan this step
        while (true) {
            // row loads (issued first; settle/vb in shadow + cross-wave overlap)
            double cd[CPT];
            if (F64) {
                const double2* rp = (const double2*)((const double*)costv
                                    + (size_t)(inext - 1) * M_PR + colbase);
                double2 t0v = rp[0], t1v = rp[1];
                cd[0] = t0v.x; cd[1] = t0v.y; cd[2] = t1v.x; cd[3] = t1v.y;
            } else {
                const float4* rp = (const float4*)((const float*)costv
                                   + (size_t)(inext - 1) * M_PR + colbase);
                float4 tv = rp[0];
                cd[0] = (double)tv.x; cd[1] = (double)tv.y;
                cd[2] = (double)tv.z; cd[3] = (double)tv.w;
            }
            double ui = u[inext];               // LDS broadcast

            // settle previous winner j0 (owner thread only)
            if (j0 > 0 && ((j0 - 1) >> 2) == tid) {
                const int okk = (j0 - 1) & 3;
                markD_lds[j0] = D;
                #pragma unroll
                for (int k = 0; k < CPT; ++k) {
                    if (k == okk) {
                        vsave_lds[j0] = v[k];
                        v[k] = NEGINF;          // cur = +inf henceforth
                        A[k] = INFD;            // never a candidate again
                        usedmask |= (1u << k);
                    }
                }
            }

            // vb = v + base2 (load-independent); cur = cd - vb (uniform formula)
            double base2 = ui - D;
            double vb[CPT];
            #pragma unroll
            for (int k = 0; k < CPT; ++k) vb[k] = v[k] + base2;

            // relax (ties cur==A[k] keep OLD parent: strict <)
            #pragma unroll
            for (int k = 0; k < CPT; ++k) {
                double cur = cd[k] - vb[k];
                bool upd = (cur < A[k]);        // settled: cur=+inf -> false
                A[k]  = upd ? cur : A[k];
                bw[k] = upd ? j0  : bw[k];
            }
            // combined post-relax tournament (strict <, ascending k =>
            // smallest col on exact tie == reference first-occurrence argmin)
            double   bA  = INFD;
            unsigned bcw = 0xFFFFFFFFu;
            #pragma unroll
            for (int k = 0; k < CPT; ++k) {
                unsigned cwk = ((unsigned)(colbase + k + 1) << 11) | (unsigned)bw[k];
                bool tk = A[k] < bA;
                bA  = tk ? A[k] : bA;
                bcw = tk ? cwk  : bcw;
            }

            // per-lane p-prefetch of MY best col (p invariant inside search)
            int mycol = (int)(bcw >> 11);
            int pf = p[(mycol > M_PR) ? 0 : mycol];

            // intra-wave value-only DPP min reduce -> lane 63
            double red = bA;
            DPPMIN(red, 0x111, 0xf, 0xf);       // row_shr:1
            DPPMIN(red, 0x112, 0xf, 0xf);       // row_shr:2
            DPPMIN(red, 0x114, 0xf, 0xe);       // row_shr:4
            DPPMIN(red, 0x118, 0xf, 0xc);       // row_shr:8
            DPPMIN(red, 0x142, 0xa, 0xf);       // row_bcast:15
            DPPMIN(red, 0x143, 0xc, 0xf);       // row_bcast:31
            double Dw = __hiloint2double(
                __builtin_amdgcn_readlane(__double2hiint(red), 63),
                __builtin_amdgcn_readlane(__double2loint(red), 63));
            unsigned long long mm = __ballot(bA == Dw);   // wave-scoped
            int wl = __builtin_ctzll(mm);                 // lowest lane = smallest col
            unsigned rcw = (unsigned)__builtin_amdgcn_readlane((int)bcw, wl);
            int      pfw = __builtin_amdgcn_readlane(pf, wl);
            if (lane == 0) {
                double2 rec;
                rec.x = Dw;
                rec.y = __hiloint2double((int)rcw, (int)pfw);
                wb[par][wid] = rec;
            }
            __syncthreads();
            // cross-wave merge: 3-compare tree, NO col compares (wave w owns
            // ascending col range => value-tie -> earlier wave = smaller col)
            double2 r0 = wb[par][0], r1 = wb[par][1];
            double2 r2 = wb[par][2], r3 = wb[par][3];
            par ^= 1;
            bool b01 = r1.x < r0.x;             // tie -> r0 (smaller cols)
            double  v01 = b01 ? r1.x : r0.x;
            double  y01 = b01 ? r1.y : r0.y;
            bool b23 = r3.x < r2.x;             // tie -> r2
            double  v23 = b23 ? r3.x : r2.x;
            double  y23 = b23 ? r3.y : r2.y;
            bool bf = v23 < v01;                // tie -> 01 side
            D           = bf ? v23 : v01;
            double ymrg = bf ? y23 : y01;
            unsigned mcw = (unsigned)__double2hiint(ymrg);
            int      mpf = __double2loint(ymrg);

            int j1 = (int)(mcw >> 11);
            if (tid == 0) way[j1] = (int)(mcw & 2047u);
            j0 = j1;
            if (mpf == 0) break;                // reached a free column (uniform)
            inext = mpf;
        }
        // ---- deferred dual flush (pre-augmentation p) ----
        if (tid == 0) u[i] += D;                // virtual col 0: markD = 0
        #pragma unroll
        for (int k = 0; k < CPT; ++k) {
            if ((usedmask >> k) & 1u) {
                const int col = colbase + k + 1;
                double adj = D - markD_lds[col];
                v[k] = vsave_lds[col] - adj;    // restore + adjust
                int r = p[col];                 // distinct rows -> distinct u addrs
                u[r] += adj;
            }
        }
        __syncthreads();
        // ---- augmentation: collect path, then parallel apply (old reads) ----
        if (tid == 0) {
            int L = 0, jj = j0;
            while (jj != 0) { pathbuf[L++] = jj; jj = way[jj]; }
            pathlen_s = L;
        }
        // prefetch next search's first row while tid 0 walks
        if (t + 1 < nfree) {
            int nr = freeA[t + 1];
            if (F64) {
                const double* nrow = (const double*)costv + (size_t)(nr - 1) * M_PR + colbase;
                double t0v = nrow[0];
                asm volatile("" :: "v"(t0v));
            } else {
                const float* nrow = (const float*)costv + (size_t)(nr - 1) * M_PR + colbase;
                float t0v = nrow[0];
                asm volatile("" :: "v"(t0v));
            }
        }
        __syncthreads();
        const int L = pathlen_s;                // L <= 257
        int d0 = -1, s0 = 0, d1 = -1, s1 = 0;
        { int tt = tid;       if (tt < L) { d0 = pathbuf[tt]; s0 = (tt == L-1) ? i : p[pathbuf[tt+1]]; } }
        { int tt = tid + 256; if (tt < L) { d1 = pathbuf[tt]; s1 = (tt == L-1) ? i : p[pathbuf[tt+1]]; } }
        __syncthreads();
        if (d0 >= 0) p[d0] = s0;
        if (d1 >= 0) p[d1] = s1;
        __syncthreads();
    }

    // ---- gather + outputs ----
    #pragma unroll
    for (int k = 0; k < CPT; ++k) {
        int j  = colbase + k + 1;
        int pr = p[j];
        if (pr > 0) colarr[pr - 1] = j - 1;
    }
    __syncthreads();

    out[tid]        = (float)tid;               // row = arange(256)
    out[N_GT + tid] = (float)colarr[tid];       // col
    if (tid < 64) {                             // cost sum by wave 0
        float s = 0.f;
        for (int idx = lane; idx < N_GT; idx += 64) {
            int c = colarr[idx];
            c = (c < 0) ? 0 : (c >= M_PR ? M_PR - 1 : c);
            float dx = cgt[2 * idx]     - cpred[2 * c];
            float dy = cgt[2 * idx + 1] - cpred[2 * c + 1];
            s += sqrtf(dx * dx + dy * dy);
        }
        #pragma unroll
        for (int off = 1; off < 64; off <<= 1) s += __shfl_xor(s, off, 64);
        if (lane == 0) out[2 * N_GT] = s;
    }
}

extern "C" void kernel_launch(void* const* d_in, const int* in_sizes, int n_in,
                              void* d_out, int out_size, void* d_ws, size_t ws_size,
                              hipStream_t stream)
{
    const float* cgt   = (const float*)d_in[0];   // (256, 2)
    const float* cpred = (const float*)d_in[1];   // (1024, 2)
    const float* lgt   = (const float*)d_in[2];   // (256, 91)
    const float* lpred = (const float*)d_in[3];   // (1024, 91)
    float* out  = (float*)d_out;                  // 513 floats

    char* ws = (char*)d_ws;
    const size_t mat64 = (size_t)N_GT * M_PR * 8;           // 2 MB
    const size_t mat32 = (size_t)N_GT * M_PR * 4;           // 1 MB

    if (ws_size >= mat64 + 4096) {
        void*  cost   = (void*)ws;
        float* rowmin = (float*)(ws + mat64);
        int*   rowarg = (int*)  (ws + mat64 + 1024);
        cost_kernel<1><<<N_GT, 256, 0, stream>>>(cgt, cpred, lgt, lpred, cost, rowmin, rowarg);
        lsa_kernel<1><<<1, 256, 0, stream>>>(cost, rowmin, rowarg, cgt, cpred, out);
    } else {
        void*  cost   = (void*)ws;
        float* rowmin = (float*)(ws + mat32);
        int*   rowarg = (int*)  (ws + mat32 + 1024);
        cost_kernel<0><<<N_GT, 256, 0, stream>>>(cgt, cpred, lgt, lpred, cost, rowmin, rowarg);
        lsa_kernel<0><<<1, 256, 0, stream>>>(cost, rowmin, rowarg, cgt, cpred, out);
    }
}